// Round 1
// baseline (296.064 us; speedup 1.0000x reference)
//
#include <hip/hip_runtime.h>
#include <hip/hip_bf16.h>
#include <cstdint>
#include <cstddef>

// ---------------------------------------------------------------------------
// bi_Mlp (fp32 I/O): out = binlin2( clip(gelu(binlin1(x))) )
// R6 -> R7:
//  * Both GEMMs ported from the 128^2 / 4-wave / __syncthreads-drain structure
//    (ceiling ~900 TF; measured 597 TF, MfmaUtil 25%) to the 256^2 / 8-wave /
//    BK=64 phase-split schedule with COUNTED vmcnt (T3+T4) + setprio (T5):
//    4 phases per K-tile, each {ds_read subtile || 2x global_load_lds ->
//    s_barrier -> lgkmcnt(0) -> 16 MFMA -> s_barrier}; one vmcnt(6) per
//    K-tile, never vmcnt(0) in steady state. 128 KiB LDS double buffer
//    (dynamic, hipFuncSetAttribute), 1 block/CU.
//  * Data path unchanged from verified R6: same 16x16x32 MFMA fragment
//    mapping, same XOR-swizzled LDS chunks (slot s of row r holds k-chunk
//    s^(r&7), 0 bank conflicts measured), same global_load_lds staging
//    (pre-swizzled global source, linear LDS dest), same fp32 alpha/bias +
//    exact-erf gelu epilogue.
//  * Bijective XCD remap (m204): GEMM2 T=150 is not 8-divisible.
// ---------------------------------------------------------------------------

typedef __bf16 bf16x8 __attribute__((ext_vector_type(8)));
typedef __bf16 bf16x4 __attribute__((ext_vector_type(4)));
typedef float floatx4 __attribute__((ext_vector_type(4)));

__device__ __forceinline__ void async_load16(const void* g, void* l) {
    __builtin_amdgcn_global_load_lds(
        (const __attribute__((address_space(1))) void*)g,
        (__attribute__((address_space(3))) void*)l,
        16, 0, 0);
}

// Merged prep: blocks [0,ncvt) convert x fp32->bf16 (4 elem/thread);
// blocks [ncvt, ncvt+3072) binarize w1 row; rest binarize w2 row.
__global__ __launch_bounds__(256) void prep_all(
    const float* __restrict__ x,
    const float* __restrict__ w1,
    const float* __restrict__ w2,
    __hip_bfloat16* __restrict__ xb,
    __hip_bfloat16* __restrict__ sgn1, float* __restrict__ alpha1,
    __hip_bfloat16* __restrict__ sgn2, float* __restrict__ alpha2,
    int ncvt)
{
    const int b = blockIdx.x;
    if (b < ncvt) {
        const int i = b * 256 + threadIdx.x;   // ncvt*256 == n4 exactly
        float4 v = ((const float4*)x)[i];
        bf16x4 o;
        o[0] = (__bf16)v.x; o[1] = (__bf16)v.y;
        o[2] = (__bf16)v.z; o[3] = (__bf16)v.w;
        ((bf16x4*)xb)[i] = o;
        return;
    }
    const float* w; __hip_bfloat16* sgn; float* alpha; int cols4; int row;
    if (b < ncvt + 3072) {
        w = w1; sgn = sgn1; alpha = alpha1; cols4 = 192; row = b - ncvt;
    } else {
        w = w2; sgn = sgn2; alpha = alpha2; cols4 = 768; row = b - ncvt - 3072;
    }
    const float4* wr = (const float4*)w + (size_t)row * cols4;
    bf16x4* sr = (bf16x4*)sgn + (size_t)row * cols4;
    float s = 0.0f;
    for (int c = threadIdx.x; c < cols4; c += 256) {
        float4 v = wr[c];
        s += fabsf(v.x) + fabsf(v.y) + fabsf(v.z) + fabsf(v.w);
        bf16x4 o;
        o[0] = (__bf16)(v.x > 0.0f ? 1.0f : (v.x < 0.0f ? -1.0f : 0.0f));
        o[1] = (__bf16)(v.y > 0.0f ? 1.0f : (v.y < 0.0f ? -1.0f : 0.0f));
        o[2] = (__bf16)(v.z > 0.0f ? 1.0f : (v.z < 0.0f ? -1.0f : 0.0f));
        o[3] = (__bf16)(v.w > 0.0f ? 1.0f : (v.w < 0.0f ? -1.0f : 0.0f));
        sr[c] = o;
    }
    #pragma unroll
    for (int off = 32; off > 0; off >>= 1) s += __shfl_down(s, off, 64);
    __shared__ float wsum[4];
    const int lane = threadIdx.x & 63;
    const int wv = threadIdx.x >> 6;
    if (lane == 0) wsum[wv] = s;
    __syncthreads();
    if (threadIdx.x == 0) {
        float t = wsum[0] + wsum[1] + wsum[2] + wsum[3];
        alpha[row] = t / (float)(cols4 * 4);
    }
}

__device__ __forceinline__ void store_val(__hip_bfloat16* C, size_t idx, float v) {
    C[idx] = __float2bfloat16(v);
}
__device__ __forceinline__ void store_val(float* C, size_t idx, float v) {
    C[idx] = v;
}

// C[M,N] = (A[M,K] . S[N,K]^T) * alpha[N] + bias[N]  (+ optional gelu/clip)
// 256x256 tile, BK=64, 8 waves (2M x 4N), per-wave output 128x64.
// LDS: 2 x (A 32KB + B 32KB) = 128 KiB dynamic, XOR-swizzled chunks.
// Phase schedule per K-tile i (buf p = i&1):
//   ph0: ds A-half0(8 b128) + B-half0(4) ; stage B-hi(i+1)->buf p^1 ; bar/MFMA
//   ph1: ds B-half1(4)                   ; stage A-lo(i+2)->buf p   ; bar/MFMA
//   ph2: ds A-half1(8)                   ; stage B-lo(i+2)->buf p   ; bar/MFMA
//   ph3: (regs only)                     ; stage A-hi(i+2)->buf p   ; vmcnt(6)
// Each staged region was last ds_read >=1 phase earlier (freed by that
// phase's lgkmcnt(0)+barrier). vmcnt(6) = the 6 loads issued after tile
// i+1's last chunk -> tile i+1 fully resident; loads stay in flight across
// barriers. Requires NT = K/64 >= 2 (here 12 and 48).
template <bool DO_GELU, typename OutT>
__global__ __launch_bounds__(512, 2) void gemm_bin(
    const __hip_bfloat16* __restrict__ A,
    const __hip_bfloat16* __restrict__ S,
    const float* __restrict__ alpha,
    const float* __restrict__ bias,
    OutT* __restrict__ C,
    int M, int N, int K, int T)
{
    extern __shared__ __align__(16) __hip_bfloat16 lds[];  // 65536 elems = 128 KiB

    // bijective XCD remap (m204): blocks with b%8==x land on XCD x; give each
    // XCD a contiguous n-fastest l-range so A-panel consumers share one L2.
    const int b = blockIdx.x;
    const int xcd = b & 7, rest = b >> 3;
    const int q8 = T >> 3, r8 = T & 7;
    const int l = (xcd < r8 ? xcd * (q8 + 1) : r8 * (q8 + 1) + (xcd - r8) * q8) + rest;
    if (l >= T) return;
    const int NTL = N >> 8;
    const int mt = l / NTL;
    const int nt = l - mt * NTL;
    const int bm = mt << 8;
    const int bn = nt << 8;

    const int tid = threadIdx.x;
    const int w = tid >> 6;
    const int lane = tid & 63;
    const int wm = w & 1;        // wave owns rows bm + wm*128 .. +128
    const int wn = w >> 1;       // wave owns cols bn + wn*64  .. +64
    const int lr = lane & 15;
    const int kq = lane >> 4;    // 0..3: 8-elem k-chunk within 32-step
    const int e3 = lr & 7;       // swizzle class
    const int crow = lane >> 3;  // staging: row within 8-row segment
    const int ccol = ((lane & 7) ^ crow) << 3;  // pre-swizzled global chunk

    const int NT = K >> 6;

    // staging segment ids (wave-uniform; seg covers tile rows seg*8..+8)
    const int idx0 = w << 1;
    const int sALo0 = (w < 4) ? idx0 : idx0 + 8;   // segs {0..7,16..23}
    const int sAHi0 = sALo0 + 8;                   // segs {8..15,24..31}
    const int sBLo0 = (w >> 1) * 8 + (w & 1) * 2;  // segs {0-3,8-11,16-19,24-27}
    const int sBHi0 = sBLo0 + 4;                   // segs {4-7,12-15,20-23,28-31}

    const int aoff  = (wm * 128 + lr) * 64;
    const int boff0 = (wn * 64 + lr) * 64;
    const int k0off = (kq ^ e3) * 8;   // slot for ks=0
    const int k1off = k0off ^ 32;      // slot for ks=1 ((4|kq)^e3)*8

    floatx4 acc[8][4];
    #pragma unroll
    for (int i = 0; i < 8; ++i)
        #pragma unroll
        for (int j = 0; j < 4; ++j)
            #pragma unroll
            for (int r = 0; r < 4; ++r) acc[i][j][r] = 0.0f;

    bf16x8 aH[4][2];   // current A-half fragments
    bf16x8 bF[4][2];   // all 4 B fragments, register-cached per tile

#define STA(dst, k0_, seg) do {                                             \
    int r_ = bm + (seg) * 8 + crow; r_ = r_ < M ? r_ : M - 1;               \
    async_load16(A + (size_t)r_ * K + ((k0_) + ccol),                       \
                 (void*)((dst) + (seg) * 512));                             \
} while (0)
#define STB(dst, k0_, seg) do {                                             \
    const int r_ = bn + (seg) * 8 + crow;                                   \
    async_load16(S + (size_t)r_ * K + ((k0_) + ccol),                       \
                 (void*)((dst) + (seg) * 512));                             \
} while (0)
#define LDA4(hbase)                                                         \
    _Pragma("unroll")                                                       \
    for (int a2 = 0; a2 < 4; ++a2) {                                        \
        const __hip_bfloat16* pa_ = bufA + aoff + ((hbase) + a2) * 1024;    \
        aH[a2][0] = *(const bf16x8*)(pa_ + k0off);                          \
        aH[a2][1] = *(const bf16x8*)(pa_ + k1off);                          \
    }
#define LDB2(bcbase)                                                        \
    _Pragma("unroll")                                                       \
    for (int b2 = 0; b2 < 2; ++b2) {                                        \
        const __hip_bfloat16* pb_ = bufB + boff0 + ((bcbase) + b2) * 1024;  \
        bF[(bcbase) + b2][0] = *(const bf16x8*)(pb_ + k0off);               \
        bF[(bcbase) + b2][1] = *(const bf16x8*)(pb_ + k1off);               \
    }
#define MM8(arb, bcb)                                                       \
    _Pragma("unroll")                                                       \
    for (int a2 = 0; a2 < 4; ++a2) {                                        \
        _Pragma("unroll")                                                   \
        for (int b2 = 0; b2 < 2; ++b2) {                                    \
            acc[(arb) + a2][(bcb) + b2] =                                   \
                __builtin_amdgcn_mfma_f32_16x16x32_bf16(                    \
                    aH[a2][0], bF[(bcb) + b2][0],                           \
                    acc[(arb) + a2][(bcb) + b2], 0, 0, 0);                  \
            acc[(arb) + a2][(bcb) + b2] =                                   \
                __builtin_amdgcn_mfma_f32_16x16x32_bf16(                    \
                    aH[a2][1], bF[(bcb) + b2][1],                           \
                    acc[(arb) + a2][(bcb) + b2], 0, 0, 0);                  \
        }                                                                   \
    }

    // ---- prologue: tile0 fully -> buf0 (8 loads); tile1 {A-lo,B-lo,A-hi}
    //      -> buf1 (6 loads; its B-hi is staged at tile0 ph0).
    {
        __hip_bfloat16* a0 = lds;
        __hip_bfloat16* b0 = lds + 16384;
        STA(a0, 0, sALo0); STA(a0, 0, sALo0 + 1);
        STB(b0, 0, sBLo0); STB(b0, 0, sBLo0 + 1);
        STA(a0, 0, sAHi0); STA(a0, 0, sAHi0 + 1);
        STB(b0, 0, sBHi0); STB(b0, 0, sBHi0 + 1);
        __hip_bfloat16* a1 = lds + 32768;
        __hip_bfloat16* b1 = lds + 49152;
        STA(a1, 64, sALo0); STA(a1, 64, sALo0 + 1);
        STB(b1, 64, sBLo0); STB(b1, 64, sBLo0 + 1);
        STA(a1, 64, sAHi0); STA(a1, 64, sAHi0 + 1);
        asm volatile("s_waitcnt vmcnt(6)" ::: "memory");  // tile0 resident
        __builtin_amdgcn_sched_barrier(0);
        __builtin_amdgcn_s_barrier();
    }

    for (int i = 0; i < NT; ++i) {
        const int p = i & 1;
        __hip_bfloat16* bufA = lds + p * 32768;
        __hip_bfloat16* bufB = bufA + 16384;
        __hip_bfloat16* othB = lds + (p ^ 1) * 32768 + 16384;
        const int kn1 = (i + 1) << 6;
        const int kn2 = (i + 2) << 6;
        const bool s1 = (i + 1) < NT;
        const bool s2 = (i + 2) < NT;

        // ---- phase 0: ds A-half0 + B-half0 ; stage B-hi(i+1) -> other buf
        LDA4(0);
        LDB2(0);
        if (s1) { STB(othB, kn1, sBHi0); STB(othB, kn1, sBHi0 + 1); }
        __builtin_amdgcn_s_barrier();
        asm volatile("s_waitcnt lgkmcnt(0)" ::: "memory");
        __builtin_amdgcn_sched_barrier(0);
        __builtin_amdgcn_s_setprio(1);
        MM8(0, 0);
        __builtin_amdgcn_s_setprio(0);
        __builtin_amdgcn_s_barrier();

        // ---- phase 1: ds B-half1 ; stage A-lo(i+2) -> this buf (freed ph0)
        LDB2(2);
        if (s2) { STA(bufA, kn2, sALo0); STA(bufA, kn2, sALo0 + 1); }
        __builtin_amdgcn_s_barrier();
        asm volatile("s_waitcnt lgkmcnt(0)" ::: "memory");
        __builtin_amdgcn_sched_barrier(0);
        __builtin_amdgcn_s_setprio(1);
        MM8(0, 2);
        __builtin_amdgcn_s_setprio(0);
        __builtin_amdgcn_s_barrier();

        // ---- phase 2: ds A-half1 ; stage B-lo(i+2) -> this buf (freed ph0)
        LDA4(4);
        if (s2) { STB(bufB, kn2, sBLo0); STB(bufB, kn2, sBLo0 + 1); }
        __builtin_amdgcn_s_barrier();
        asm volatile("s_waitcnt lgkmcnt(0)" ::: "memory");
        __builtin_amdgcn_sched_barrier(0);
        __builtin_amdgcn_s_setprio(1);
        MM8(4, 2);
        __builtin_amdgcn_s_setprio(0);
        __builtin_amdgcn_s_barrier();

        // ---- phase 3: regs only ; stage A-hi(i+2) (freed ph2) ; counted vmcnt
        if (s2) { STA(bufA, kn2, sAHi0); STA(bufA, kn2, sAHi0 + 1); }
        if (s1) {
            if (s2) asm volatile("s_waitcnt vmcnt(6)" ::: "memory");
            else    asm volatile("s_waitcnt vmcnt(0)" ::: "memory");
            __builtin_amdgcn_sched_barrier(0);
        }
        __builtin_amdgcn_s_barrier();
        __builtin_amdgcn_s_setprio(1);
        MM8(4, 0);
        __builtin_amdgcn_s_setprio(0);
        __builtin_amdgcn_s_barrier();
    }

#undef STA
#undef STB
#undef LDA4
#undef LDB2
#undef MM8

    // ---- epilogue: alpha/bias fp32, optional exact-erf gelu + clip
    float al[4], bi[4];
    #pragma unroll
    for (int bc = 0; bc < 4; ++bc) {
        const int col = bn + wn * 64 + bc * 16 + lr;
        al[bc] = alpha[col];
        bi[bc] = bias[col];
    }
    #pragma unroll
    for (int ar = 0; ar < 8; ++ar) {
        const int row0 = bm + wm * 128 + ar * 16 + kq * 4;
        #pragma unroll
        for (int r = 0; r < 4; ++r) {
            const int row = row0 + r;
            if (row < M) {
                #pragma unroll
                for (int bc = 0; bc < 4; ++bc) {
                    float v = acc[ar][bc][r] * al[bc] + bi[bc];
                    if (DO_GELU) {
                        v = 0.5f * v * (1.0f + erff(v * 0.70710678118654752f));
                        v = fminf(fmaxf(v, -10.0f), 10.0f);
                    }
                    store_val(C, (size_t)row * N + (bn + wn * 64 + bc * 16 + lr), v);
                }
            }
        }
    }
}

extern "C" void kernel_launch(void* const* d_in, const int* in_sizes, int n_in,
                              void* d_out, int out_size, void* d_ws, size_t ws_size,
                              hipStream_t stream) {
    const float* x  = (const float*)d_in[0];
    const float* w1 = (const float*)d_in[1];
    const float* b1 = (const float*)d_in[2];
    const float* w2 = (const float*)d_in[3];
    const float* b2 = (const float*)d_in[4];

    const int M = 64 * 197;   // 12608
    const int Cd = 768;
    const int Hd = 3072;

    // workspace layout (~106 MB total)
    char* ws = (char*)d_ws;
    __hip_bfloat16* xb   = (__hip_bfloat16*)ws;                 // [M, Cd]
    __hip_bfloat16* sgn1 = xb + (size_t)M * Cd;                 // [Hd, Cd]
    __hip_bfloat16* sgn2 = sgn1 + (size_t)Hd * Cd;              // [Cd, Hd]
    float* alpha1 = (float*)(sgn2 + (size_t)Cd * Hd);           // [Hd]
    float* alpha2 = alpha1 + Hd;                                // [Cd]
    __hip_bfloat16* hbuf = (__hip_bfloat16*)(alpha2 + Cd);      // [M, Hd]

    const int ncvt = (M * Cd) / 4 / 256;   // 9456 (exact)
    prep_all<<<ncvt + Hd + Cd, 256, 0, stream>>>(
        x, w1, w2, xb, sgn1, alpha1, sgn2, alpha2, ncvt);

    const int gm = (M + 255) / 256;        // 50 (last tile: 64 valid rows)

    // GEMM1: 12 x 50 = 600 tiles, K-tiles = 12
    {
        const int T = (Hd / 256) * gm;
        hipFuncSetAttribute(
            reinterpret_cast<const void*>(&gemm_bin<true, __hip_bfloat16>),
            hipFuncAttributeMaxDynamicSharedMemorySize, 131072);
        gemm_bin<true, __hip_bfloat16><<<T, 512, 131072, stream>>>(
            xb, sgn1, alpha1, b1, hbuf, M, Hd, Cd, T);
    }
    // GEMM2: 3 x 50 = 150 tiles, K-tiles = 48
    {
        const int T = (Cd / 256) * gm;
        hipFuncSetAttribute(
            reinterpret_cast<const void*>(&gemm_bin<false, float>),
            hipFuncAttributeMaxDynamicSharedMemorySize, 131072);
        gemm_bin<false, float><<<T, 512, 131072, stream>>>(
            hbuf, sgn2, alpha2, b2, (float*)d_out, M, Cd, Hd, T);
    }
}

// Round 2
// 278.266 us; speedup vs baseline: 1.0640x; 1.0640x over previous
//
#include <hip/hip_runtime.h>
#include <hip/hip_bf16.h>
#include <cstdint>
#include <cstddef>

// ---------------------------------------------------------------------------
// bi_Mlp (fp32 I/O): out = binlin2( clip(gelu(binlin1(x))) )
// R7 -> R8 (post-mortem: 256^2 8-phase regressed G1 99.7->125, MfmaUtil 25->19;
// causes: 600-block grid = 2.34/CU at 1 block/CU residency (3-round quant,
// no co-residency overlap) + NT=12 too short to amortize the pipeline):
//  * GEMM2: reverted to the proven R6 128^2 / 4-wave / 3-blocks-per-CU kernel
//    (measured ~99 us; R7's 150-block 256^2 left 41% of CUs idle).
//  * GEMM1: counted-vmcnt 8-phase engine KEPT but reshaped to BM=128 x BN=256,
//    8 waves (per-wave 64x64, acc 64 AGPR), LDS 96 KiB dbuf -> grid 1188
//    (4.64/CU, quantization waste 22%->7%), block lifetime halved.
//    Staging 6 segs/wave/K-tile: ph0 B-hi(i+1), ph1 A-lo(i+2), ph2 B-lo(i+2),
//    ph3 A-hi(i+2) + vmcnt(4) (never 0 in steady state). Each staged region
//    freed by the phase that last ds_read it. Same verified XOR chunk swizzle.
// ---------------------------------------------------------------------------

typedef __bf16 bf16x8 __attribute__((ext_vector_type(8)));
typedef __bf16 bf16x4 __attribute__((ext_vector_type(4)));
typedef float floatx4 __attribute__((ext_vector_type(4)));

__device__ __forceinline__ void async_load16(const void* g, void* l) {
    __builtin_amdgcn_global_load_lds(
        (const __attribute__((address_space(1))) void*)g,
        (__attribute__((address_space(3))) void*)l,
        16, 0, 0);
}

// Merged prep: blocks [0,ncvt) convert x fp32->bf16 (4 elem/thread);
// blocks [ncvt, ncvt+3072) binarize w1 row; rest binarize w2 row.
__global__ __launch_bounds__(256) void prep_all(
    const float* __restrict__ x,
    const float* __restrict__ w1,
    const float* __restrict__ w2,
    __hip_bfloat16* __restrict__ xb,
    __hip_bfloat16* __restrict__ sgn1, float* __restrict__ alpha1,
    __hip_bfloat16* __restrict__ sgn2, float* __restrict__ alpha2,
    int ncvt)
{
    const int b = blockIdx.x;
    if (b < ncvt) {
        const int i = b * 256 + threadIdx.x;   // ncvt*256 == n4 exactly
        float4 v = ((const float4*)x)[i];
        bf16x4 o;
        o[0] = (__bf16)v.x; o[1] = (__bf16)v.y;
        o[2] = (__bf16)v.z; o[3] = (__bf16)v.w;
        ((bf16x4*)xb)[i] = o;
        return;
    }
    const float* w; __hip_bfloat16* sgn; float* alpha; int cols4; int row;
    if (b < ncvt + 3072) {
        w = w1; sgn = sgn1; alpha = alpha1; cols4 = 192; row = b - ncvt;
    } else {
        w = w2; sgn = sgn2; alpha = alpha2; cols4 = 768; row = b - ncvt - 3072;
    }
    const float4* wr = (const float4*)w + (size_t)row * cols4;
    bf16x4* sr = (bf16x4*)sgn + (size_t)row * cols4;
    float s = 0.0f;
    for (int c = threadIdx.x; c < cols4; c += 256) {
        float4 v = wr[c];
        s += fabsf(v.x) + fabsf(v.y) + fabsf(v.z) + fabsf(v.w);
        bf16x4 o;
        o[0] = (__bf16)(v.x > 0.0f ? 1.0f : (v.x < 0.0f ? -1.0f : 0.0f));
        o[1] = (__bf16)(v.y > 0.0f ? 1.0f : (v.y < 0.0f ? -1.0f : 0.0f));
        o[2] = (__bf16)(v.z > 0.0f ? 1.0f : (v.z < 0.0f ? -1.0f : 0.0f));
        o[3] = (__bf16)(v.w > 0.0f ? 1.0f : (v.w < 0.0f ? -1.0f : 0.0f));
        sr[c] = o;
    }
    #pragma unroll
    for (int off = 32; off > 0; off >>= 1) s += __shfl_down(s, off, 64);
    __shared__ float wsum[4];
    const int lane = threadIdx.x & 63;
    const int wv = threadIdx.x >> 6;
    if (lane == 0) wsum[wv] = s;
    __syncthreads();
    if (threadIdx.x == 0) {
        float t = wsum[0] + wsum[1] + wsum[2] + wsum[3];
        alpha[row] = t / (float)(cols4 * 4);
    }
}

__device__ __forceinline__ void store_val(__hip_bfloat16* C, size_t idx, float v) {
    C[idx] = __float2bfloat16(v);
}
__device__ __forceinline__ void store_val(float* C, size_t idx, float v) {
    C[idx] = v;
}

// ===========================================================================
// GEMM1 engine: 128x256 tile, BK=64, 8 waves (2M x 4N), per-wave 64x64.
// LDS (dynamic 96 KiB): A dbuf 2x16KB @ [0,8192) elems, B dbuf 2x32KB
// @ [16384,49152) elems. XOR-swizzled chunks: slot s of row r = chunk s^(r&7).
// ===========================================================================
template <bool DO_GELU, typename OutT>
__global__ __launch_bounds__(512, 2) void gemm_bin_8w(
    const __hip_bfloat16* __restrict__ A,
    const __hip_bfloat16* __restrict__ S,
    const float* __restrict__ alpha,
    const float* __restrict__ bias,
    OutT* __restrict__ C,
    int M, int N, int K, int T)
{
    extern __shared__ __align__(16) __hip_bfloat16 lds[];  // 49152 elems

    // bijective XCD remap (m204)
    const int b = blockIdx.x;
    const int xcd = b & 7, rest = b >> 3;
    const int q8 = T >> 3, r8 = T & 7;
    const int l = (xcd < r8 ? xcd * (q8 + 1) : r8 * (q8 + 1) + (xcd - r8) * q8) + rest;
    if (l >= T) return;
    const int NTL = N >> 8;           // n-tiles (BN=256)
    const int mt = l / NTL;
    const int nt = l - mt * NTL;
    const int bm = mt << 7;           // BM=128
    const int bn = nt << 8;

    const int tid = threadIdx.x;
    const int w = tid >> 6;
    const int lane = tid & 63;
    const int wm = w & 1;             // rows bm + wm*64 .. +64
    const int wn = w >> 1;            // cols bn + wn*64 .. +64
    const int lr = lane & 15;
    const int kq = lane >> 4;
    const int e3 = lr & 7;
    const int crow = lane >> 3;
    const int ccol = ((lane & 7) ^ crow) << 3;

    const int NT = K >> 6;

    // staging segment ids (wave-uniform). A: 16 segs (128 rows), B: 32 segs.
    const int sALo = ((w >> 2) << 3) + (w & 3);        // {0..3, 8..11}
    const int sAHi = sALo + 4;                         // {4..7, 12..15}
    const int sBLo = ((w >> 1) << 3) + ((w & 1) << 1); // 2 consecutive segs
    const int sBHi = sBLo + 4;

    const int k0off = (kq ^ e3) * 8;
    const int k1off = k0off ^ 32;

    floatx4 acc[4][4];
    #pragma unroll
    for (int i = 0; i < 4; ++i)
        #pragma unroll
        for (int j = 0; j < 4; ++j)
            #pragma unroll
            for (int r = 0; r < 4; ++r) acc[i][j][r] = 0.0f;

    bf16x8 aF[4][2];
    bf16x8 bF[4][2];

#define STA(dst, k0_, seg) do {                                             \
    int r_ = bm + (seg) * 8 + crow; r_ = r_ < M ? r_ : M - 1;               \
    async_load16(A + (size_t)r_ * K + ((k0_) + ccol),                       \
                 (void*)((dst) + (seg) * 512));                             \
} while (0)
#define STB(dst, k0_, seg) do {                                             \
    const int r_ = bn + (seg) * 8 + crow;                                   \
    async_load16(S + (size_t)r_ * K + ((k0_) + ccol),                       \
                 (void*)((dst) + (seg) * 512));                             \
} while (0)
#define LDA2(rtb)                                                           \
    _Pragma("unroll")                                                       \
    for (int a2 = 0; a2 < 2; ++a2) {                                        \
        const __hip_bfloat16* pa_ =                                         \
            bufA + (wm * 64 + ((rtb) + a2) * 16 + lr) * 64;                 \
        aF[(rtb) + a2][0] = *(const bf16x8*)(pa_ + k0off);                  \
        aF[(rtb) + a2][1] = *(const bf16x8*)(pa_ + k1off);                  \
    }
#define LDB2(ctb)                                                           \
    _Pragma("unroll")                                                       \
    for (int b2 = 0; b2 < 2; ++b2) {                                        \
        const __hip_bfloat16* pb_ =                                         \
            bufB + (wn * 64 + ((ctb) + b2) * 16 + lr) * 64;                 \
        bF[(ctb) + b2][0] = *(const bf16x8*)(pb_ + k0off);                  \
        bF[(ctb) + b2][1] = *(const bf16x8*)(pb_ + k1off);                  \
    }
#define MMQ(rtb, ctb)                                                       \
    _Pragma("unroll")                                                       \
    for (int a2 = 0; a2 < 2; ++a2) {                                        \
        _Pragma("unroll")                                                   \
        for (int b2 = 0; b2 < 2; ++b2) {                                    \
            acc[(rtb) + a2][(ctb) + b2] =                                   \
                __builtin_amdgcn_mfma_f32_16x16x32_bf16(                    \
                    aF[(rtb) + a2][0], bF[(ctb) + b2][0],                   \
                    acc[(rtb) + a2][(ctb) + b2], 0, 0, 0);                  \
            acc[(rtb) + a2][(ctb) + b2] =                                   \
                __builtin_amdgcn_mfma_f32_16x16x32_bf16(                    \
                    aF[(rtb) + a2][1], bF[(ctb) + b2][1],                   \
                    acc[(rtb) + a2][(ctb) + b2], 0, 0, 0);                  \
        }                                                                   \
    }

    // ---- prologue: tile0 -> buf0 (6/wave), tile1 {A-lo,B-lo,A-hi} -> buf1
    //      (4/wave; its B-hi staged at tile0 ph0). vmcnt(4) = tile0 resident.
    {
        __hip_bfloat16* a0 = lds;
        __hip_bfloat16* b0 = lds + 16384;
        STA(a0, 0, sALo);
        STB(b0, 0, sBLo); STB(b0, 0, sBLo + 1);
        STA(a0, 0, sAHi);
        STB(b0, 0, sBHi); STB(b0, 0, sBHi + 1);
        __hip_bfloat16* a1 = lds + 8192;
        __hip_bfloat16* b1 = lds + 32768;
        STA(a1, 64, sALo);
        STB(b1, 64, sBLo); STB(b1, 64, sBLo + 1);
        STA(a1, 64, sAHi);
        asm volatile("s_waitcnt vmcnt(4)" ::: "memory");
        __builtin_amdgcn_sched_barrier(0);
        __builtin_amdgcn_s_barrier();
    }

    for (int i = 0; i < NT; ++i) {
        const int p = i & 1;
        __hip_bfloat16* bufA = lds + p * 8192;
        __hip_bfloat16* bufB = lds + 16384 + p * 16384;
        __hip_bfloat16* othB = lds + 16384 + (p ^ 1) * 16384;
        const int kn1 = (i + 1) << 6;
        const int kn2 = (i + 2) << 6;
        const bool s1 = (i + 1) < NT;
        const bool s2 = (i + 2) < NT;

        // ph0: ds A-lo + B-lo (8 b128) ; stage B-hi(i+1) -> other buf
        LDA2(0);
        LDB2(0);
        if (s1) { STB(othB, kn1, sBHi); STB(othB, kn1, sBHi + 1); }
        __builtin_amdgcn_s_barrier();
        asm volatile("s_waitcnt lgkmcnt(0)" ::: "memory");
        __builtin_amdgcn_sched_barrier(0);
        __builtin_amdgcn_s_setprio(1);
        MMQ(0, 0);
        __builtin_amdgcn_s_setprio(0);
        __builtin_amdgcn_s_barrier();

        // ph1: ds B-hi ; stage A-lo(i+2) -> this buf (A-lo freed by ph0)
        LDB2(2);
        if (s2) STA(bufA, kn2, sALo);
        __builtin_amdgcn_s_barrier();
        asm volatile("s_waitcnt lgkmcnt(0)" ::: "memory");
        __builtin_amdgcn_sched_barrier(0);
        __builtin_amdgcn_s_setprio(1);
        MMQ(0, 2);
        __builtin_amdgcn_s_setprio(0);
        __builtin_amdgcn_s_barrier();

        // ph2: ds A-hi ; stage B-lo(i+2) -> this buf (B-lo freed by ph0)
        LDA2(2);
        if (s2) { STB(bufB, kn2, sBLo); STB(bufB, kn2, sBLo + 1); }
        __builtin_amdgcn_s_barrier();
        asm volatile("s_waitcnt lgkmcnt(0)" ::: "memory");
        __builtin_amdgcn_sched_barrier(0);
        __builtin_amdgcn_s_setprio(1);
        MMQ(2, 2);
        __builtin_amdgcn_s_setprio(0);
        __builtin_amdgcn_s_barrier();

        // ph3: regs only ; stage A-hi(i+2) (freed by ph2) ; counted vmcnt
        if (s2) STA(bufA, kn2, sAHi);
        if (s1) {
            if (s2) asm volatile("s_waitcnt vmcnt(4)" ::: "memory");
            else    asm volatile("s_waitcnt vmcnt(0)" ::: "memory");
            __builtin_amdgcn_sched_barrier(0);
        }
        __builtin_amdgcn_s_barrier();
        __builtin_amdgcn_s_setprio(1);
        MMQ(2, 0);
        __builtin_amdgcn_s_setprio(0);
        __builtin_amdgcn_s_barrier();
    }

#undef STA
#undef STB
#undef LDA2
#undef LDB2
#undef MMQ

    // ---- epilogue
    float al[4], bi[4];
    #pragma unroll
    for (int bc = 0; bc < 4; ++bc) {
        const int col = bn + wn * 64 + bc * 16 + lr;
        al[bc] = alpha[col];
        bi[bc] = bias[col];
    }
    #pragma unroll
    for (int ar = 0; ar < 4; ++ar) {
        const int row0 = bm + wm * 64 + ar * 16 + kq * 4;
        #pragma unroll
        for (int r = 0; r < 4; ++r) {
            const int row = row0 + r;
            if (row < M) {
                #pragma unroll
                for (int bc = 0; bc < 4; ++bc) {
                    float v = acc[ar][bc][r] * al[bc] + bi[bc];
                    if (DO_GELU) {
                        v = 0.5f * v * (1.0f + erff(v * 0.70710678118654752f));
                        v = fminf(fmaxf(v, -10.0f), 10.0f);
                    }
                    store_val(C, (size_t)row * N + (bn + wn * 64 + bc * 16 + lr), v);
                }
            }
        }
    }
}

// ===========================================================================
// GEMM2 engine (R6, proven ~99 us): 128x128 tile, K-step 64, 4 waves (2x2),
// 32 KiB static LDS, ~3 blocks/CU co-residency. XOR-swizzled chunks.
// 1-D grid, XCD-banded: l=(b&7)*perXcd+(b>>3).
// ===========================================================================
template <bool DO_GELU, typename OutT>
__global__ __launch_bounds__(256) void gemm_bin_128(
    const __hip_bfloat16* __restrict__ A,
    const __hip_bfloat16* __restrict__ S,
    const float* __restrict__ alpha,
    const float* __restrict__ bias,
    OutT* __restrict__ C,
    int M, int N, int K, int T, int perXcd)
{
    constexpr int TM = 128;
    constexpr int TN = 128;
    constexpr int TK = 64;

    const int b = blockIdx.x;
    const int l = (b & 7) * perXcd + (b >> 3);
    if (l >= T) return;
    const int NT = N / TN;
    const int mt = l / NT;
    const int nt = l - mt * NT;
    const int bm = mt * TM;
    const int bn = nt * TN;

    __shared__ __align__(16) __hip_bfloat16 sA[TM * TK];
    __shared__ __align__(16) __hip_bfloat16 sB[TN * TK];

    const int tid = threadIdx.x;
    const int wave = tid >> 6;
    const int lane = tid & 63;

    const int wm = (wave & 1) * 64;
    const int wn = (wave >> 1) * 64;
    const int lr = lane & 15;
    const int kq = lane >> 4;
    const int e3 = lr & 7;

    const int crow = lane >> 3;
    const int ccol = ((lane & 7) ^ crow) * 8;

    floatx4 acc[4][4];
    #pragma unroll
    for (int i = 0; i < 4; i++)
        #pragma unroll
        for (int j = 0; j < 4; j++)
            #pragma unroll
            for (int r = 0; r < 4; r++)
                acc[i][j][r] = 0.0f;

    for (int k0 = 0; k0 < K; k0 += TK) {
        #pragma unroll
        for (int t = 0; t < 8; t++) {
            const int seg = wave * 8 + t;
            if (seg < 16) {
                const int r = seg * 8 + crow;
                int ar = bm + r;
                ar = ar < M ? ar : (M - 1);
                async_load16(A + (size_t)ar * K + (k0 + ccol), (void*)(sA + seg * 512));
            } else {
                const int r = (seg - 16) * 8 + crow;
                async_load16(S + (size_t)(bn + r) * K + (k0 + ccol),
                             (void*)(sB + (seg - 16) * 512));
            }
        }
        __syncthreads();

        #pragma unroll
        for (int ks = 0; ks < 2; ks++) {
            const int slot = ((ks << 2) | kq) ^ e3;
            bf16x8 af[4], bfv[4];
            #pragma unroll
            for (int i = 0; i < 4; i++)
                af[i] = *(const bf16x8*)(sA + (wm + i * 16 + lr) * TK + slot * 8);
            #pragma unroll
            for (int j = 0; j < 4; j++)
                bfv[j] = *(const bf16x8*)(sB + (wn + j * 16 + lr) * TK + slot * 8);
            #pragma unroll
            for (int i = 0; i < 4; i++)
                #pragma unroll
                for (int j = 0; j < 4; j++)
                    acc[i][j] = __builtin_amdgcn_mfma_f32_16x16x32_bf16(
                        af[i], bfv[j], acc[i][j], 0, 0, 0);
        }
        __syncthreads();
    }

    float al[4], bi[4];
    #pragma unroll
    for (int j = 0; j < 4; j++) {
        const int col = bn + wn + j * 16 + lr;
        al[j] = alpha[col];
        bi[j] = bias[col];
    }
    #pragma unroll
    for (int i = 0; i < 4; i++) {
        const int row0 = bm + wm + i * 16 + kq * 4;
        #pragma unroll
        for (int r = 0; r < 4; r++) {
            const int row = row0 + r;
            if (row < M) {
                #pragma unroll
                for (int j = 0; j < 4; j++) {
                    float v = acc[i][j][r] * al[j] + bi[j];
                    if (DO_GELU) {
                        v = 0.5f * v * (1.0f + erff(v * 0.70710678118654752f));
                        v = fminf(fmaxf(v, -10.0f), 10.0f);
                    }
                    store_val(C, (size_t)row * N + (bn + wn + j * 16 + lr), v);
                }
            }
        }
    }
}

extern "C" void kernel_launch(void* const* d_in, const int* in_sizes, int n_in,
                              void* d_out, int out_size, void* d_ws, size_t ws_size,
                              hipStream_t stream) {
    const float* x  = (const float*)d_in[0];
    const float* w1 = (const float*)d_in[1];
    const float* b1 = (const float*)d_in[2];
    const float* w2 = (const float*)d_in[3];
    const float* b2 = (const float*)d_in[4];

    const int M = 64 * 197;   // 12608
    const int Cd = 768;
    const int Hd = 3072;

    // workspace layout (~106 MB total)
    char* ws = (char*)d_ws;
    __hip_bfloat16* xb   = (__hip_bfloat16*)ws;                 // [M, Cd]
    __hip_bfloat16* sgn1 = xb + (size_t)M * Cd;                 // [Hd, Cd]
    __hip_bfloat16* sgn2 = sgn1 + (size_t)Hd * Cd;              // [Cd, Hd]
    float* alpha1 = (float*)(sgn2 + (size_t)Cd * Hd);           // [Hd]
    float* alpha2 = alpha1 + Hd;                                // [Cd]
    __hip_bfloat16* hbuf = (__hip_bfloat16*)(alpha2 + Cd);      // [M, Hd]

    const int ncvt = (M * Cd) / 4 / 256;   // 9456 (exact)
    prep_all<<<ncvt + Hd + Cd, 256, 0, stream>>>(
        x, w1, w2, xb, sgn1, alpha1, sgn2, alpha2, ncvt);

    const int gm = (M + 127) / 128;        // 99

    // GEMM1: 128x256 tiles -> 99 x 12 = 1188 blocks (4.64/CU), NT=12
    {
        const int T = (Hd / 256) * gm;
        hipFuncSetAttribute(
            reinterpret_cast<const void*>(&gemm_bin_8w<true, __hip_bfloat16>),
            hipFuncAttributeMaxDynamicSharedMemorySize, 98304);
        gemm_bin_8w<true, __hip_bfloat16><<<T, 512, 98304, stream>>>(
            xb, sgn1, alpha1, b1, hbuf, M, Hd, Cd, T);
    }
    // GEMM2: 128x128 tiles -> 6 x 99 = 594 tiles; perXcd = 75, grid 600
    {
        const int T = (Cd / 128) * gm;
        const int perXcd = (T + 7) / 8;
        gemm_bin_128<false, float><<<perXcd * 8, 256, 0, stream>>>(
            hbuf, sgn2, alpha2, b2, (float*)d_out, M, Cd, Hd, T, perXcd);
    }
}

// Round 3
// 263.873 us; speedup vs baseline: 1.1220x; 1.0545x over previous
//
#include <hip/hip_runtime.h>
#include <hip/hip_bf16.h>
#include <cstdint>
#include <cstddef>

// ---------------------------------------------------------------------------
// bi_Mlp (fp32 I/O): out = binlin2( clip(gelu(binlin1(x))) )
// R8 -> R9:
//  * Phase-split engine ABANDONED (2 rounds of evidence: 125us @256^2, 119us
//    @128x256 vs R6's 99.6us plain structure; at NT=12/48 and ~600-2400 block
//    grids, 1-block/CU lockstep pipelines lose to 2-3 blocks/CU co-residency).
//    Both GEMMs byte-identical to R6 (G1 99.6us, G2 ~95-99us measured).
//  * prep_all rewritten: was 13,296 tiny blocks (4KB x-convert blocks; one
//    weight row per 256-thread block with LDS block-reduce) -> dispatch-bound,
//    est ~50-60us vs 14us BW floor (accounts for the ~60us of non-GEMM time
//    seen in R6/R7/R8). Now 2240 grid-stride blocks: x-convert 32B/thread/iter,
//    one WAVE per weight row (shfl-only reduce, no LDS/sync).
// ---------------------------------------------------------------------------

typedef __bf16 bf16x8 __attribute__((ext_vector_type(8)));
typedef __bf16 bf16x4 __attribute__((ext_vector_type(4)));
typedef float floatx4 __attribute__((ext_vector_type(4)));

__device__ __forceinline__ void async_load16(const void* g, void* l) {
    __builtin_amdgcn_global_load_lds(
        (const __attribute__((address_space(1))) void*)g,
        (__attribute__((address_space(3))) void*)l,
        16, 0, 0);
}

// Grid-stride prep: blocks [0, NBX) convert x fp32->bf16 (8 elem/thread/iter);
// blocks [NBX, NBX+960): one wave per weight row (w1 rows 0..3071, then w2).
__global__ __launch_bounds__(256) void prep_all(
    const float* __restrict__ x,
    const float* __restrict__ w1,
    const float* __restrict__ w2,
    __hip_bfloat16* __restrict__ xb,
    __hip_bfloat16* __restrict__ sgn1, float* __restrict__ alpha1,
    __hip_bfloat16* __restrict__ sgn2, float* __restrict__ alpha2,
    int nx8, int NBX)
{
    const int b = blockIdx.x;
    const int tid = threadIdx.x;
    if (b < NBX) {
        // ---- x convert: 8 floats per thread per iter, grid-stride
        const float4* xv = (const float4*)x;
        bf16x8* xo = (bf16x8*)xb;
        const int stride = NBX * 256;
        for (int i = b * 256 + tid; i < nx8; i += stride) {
            float4 a = xv[2 * i];
            float4 c = xv[2 * i + 1];
            bf16x8 o;
            o[0] = (__bf16)a.x; o[1] = (__bf16)a.y;
            o[2] = (__bf16)a.z; o[3] = (__bf16)a.w;
            o[4] = (__bf16)c.x; o[5] = (__bf16)c.y;
            o[6] = (__bf16)c.z; o[7] = (__bf16)c.w;
            xo[i] = o;
        }
        return;
    }
    // ---- weight binarize: one wave per row, shfl-only reduce
    const int lane = tid & 63;
    const int wv = tid >> 6;
    const int wr = (b - NBX) * 4 + wv;          // 0..3839
    const float* w; __hip_bfloat16* sgn; float* alpha; int cols4; int row;
    if (wr < 3072) {
        w = w1; sgn = sgn1; alpha = alpha1; cols4 = 192; row = wr;
    } else {
        w = w2; sgn = sgn2; alpha = alpha2; cols4 = 768; row = wr - 3072;
    }
    const float4* wrp = (const float4*)w + (size_t)row * cols4;
    bf16x4* sr = (bf16x4*)sgn + (size_t)row * cols4;
    float s = 0.0f;
    for (int c = lane; c < cols4; c += 64) {
        float4 v = wrp[c];
        s += fabsf(v.x) + fabsf(v.y) + fabsf(v.z) + fabsf(v.w);
        bf16x4 o;
        o[0] = (__bf16)(v.x > 0.0f ? 1.0f : (v.x < 0.0f ? -1.0f : 0.0f));
        o[1] = (__bf16)(v.y > 0.0f ? 1.0f : (v.y < 0.0f ? -1.0f : 0.0f));
        o[2] = (__bf16)(v.z > 0.0f ? 1.0f : (v.z < 0.0f ? -1.0f : 0.0f));
        o[3] = (__bf16)(v.w > 0.0f ? 1.0f : (v.w < 0.0f ? -1.0f : 0.0f));
        sr[c] = o;
    }
    #pragma unroll
    for (int off = 32; off > 0; off >>= 1) s += __shfl_down(s, off, 64);
    if (lane == 0) alpha[row] = s / (float)(cols4 * 4);
}

__device__ __forceinline__ void store_val(__hip_bfloat16* C, size_t idx, float v) {
    C[idx] = __float2bfloat16(v);
}
__device__ __forceinline__ void store_val(float* C, size_t idx, float v) {
    C[idx] = v;
}

// C[M,N] = (A[M,K] . S[N,K]^T) * alpha[N] + bias[N]  (+ optional gelu/clip)
// 128x128 tile, K-step 64, 4 waves (2x2), 16x16x32 bf16 MFMA.
// XOR-swizzled LDS: slot s of row r holds k-chunk s^(r&7) (0 conflicts).
// 1-D grid, XCD-banded: l=(b&7)*perXcd+(b>>3); m = l/NT (band), n = l%NT.
// (R6 kernel, measured 99.6us G1 / <=99 G2 — unchanged.)
template <bool DO_GELU, typename OutT>
__global__ __launch_bounds__(256) void gemm_bin(
    const __hip_bfloat16* __restrict__ A,
    const __hip_bfloat16* __restrict__ S,
    const float* __restrict__ alpha,
    const float* __restrict__ bias,
    OutT* __restrict__ C,
    int M, int N, int K, int T, int perXcd)
{
    constexpr int TM = 128;
    constexpr int TN = 128;
    constexpr int TK = 64;

    const int b = blockIdx.x;
    const int l = (b & 7) * perXcd + (b >> 3);
    if (l >= T) return;
    const int NT = N / TN;
    const int mt = l / NT;
    const int nt = l - mt * NT;
    const int bm = mt * TM;
    const int bn = nt * TN;

    __shared__ __align__(16) __hip_bfloat16 sA[TM * TK];
    __shared__ __align__(16) __hip_bfloat16 sB[TN * TK];

    const int tid = threadIdx.x;
    const int wave = tid >> 6;
    const int lane = tid & 63;

    const int wm = (wave & 1) * 64;
    const int wn = (wave >> 1) * 64;
    const int lr = lane & 15;         // m (A) / n (B) index within 16-tile
    const int kq = lane >> 4;         // 0..3: 8-elem k-chunk within 32-step
    const int e3 = lr & 7;            // swizzle class

    // staging: lane writes LDS offset lane*16B; fetch global chunk
    // (lane&7)^(lane>>3) so slot s of row r holds chunk s^(r&7)
    const int crow = lane >> 3;
    const int ccol = ((lane & 7) ^ crow) * 8;

    floatx4 acc[4][4];
    #pragma unroll
    for (int i = 0; i < 4; i++)
        #pragma unroll
        for (int j = 0; j < 4; j++)
            #pragma unroll
            for (int r = 0; r < 4; r++)
                acc[i][j][r] = 0.0f;

    for (int k0 = 0; k0 < K; k0 += TK) {
        // --- stage A (128 rows) + B (128 rows), 16B/lane async
        #pragma unroll
        for (int t = 0; t < 8; t++) {
            const int seg = wave * 8 + t;        // wave-uniform, 0..31
            if (seg < 16) {
                const int r = seg * 8 + crow;
                int ar = bm + r;
                ar = ar < M ? ar : (M - 1);      // clamp tail rows (stores guarded)
                async_load16(A + (size_t)ar * K + (k0 + ccol), (void*)(sA + seg * 512));
            } else {
                const int r = (seg - 16) * 8 + crow;
                async_load16(S + (size_t)(bn + r) * K + (k0 + ccol),
                             (void*)(sB + (seg - 16) * 512));
            }
        }
        __syncthreads();

        // --- compute: 2 k-steps of 32, 16 MFMAs each
        #pragma unroll
        for (int ks = 0; ks < 2; ks++) {
            const int slot = ((ks << 2) | kq) ^ e3;   // k-chunk kc = ks*4+kq
            bf16x8 af[4], bfv[4];
            #pragma unroll
            for (int i = 0; i < 4; i++)
                af[i] = *(const bf16x8*)(sA + (wm + i * 16 + lr) * TK + slot * 8);
            #pragma unroll
            for (int j = 0; j < 4; j++)
                bfv[j] = *(const bf16x8*)(sB + (wn + j * 16 + lr) * TK + slot * 8);
            #pragma unroll
            for (int i = 0; i < 4; i++)
                #pragma unroll
                for (int j = 0; j < 4; j++)
                    acc[i][j] = __builtin_amdgcn_mfma_f32_16x16x32_bf16(
                        af[i], bfv[j], acc[i][j], 0, 0, 0);
        }
        __syncthreads();
    }

    // --- epilogue: alpha/bias fp32, optional exact-erf gelu + clip
    float al[4], bi[4];
    #pragma unroll
    for (int j = 0; j < 4; j++) {
        const int col = bn + wn + j * 16 + lr;
        al[j] = alpha[col];
        bi[j] = bias[col];
    }
    #pragma unroll
    for (int i = 0; i < 4; i++) {
        const int row0 = bm + wm + i * 16 + kq * 4;
        #pragma unroll
        for (int r = 0; r < 4; r++) {
            const int row = row0 + r;
            if (row < M) {
                #pragma unroll
                for (int j = 0; j < 4; j++) {
                    float v = acc[i][j][r] * al[j] + bi[j];
                    if (DO_GELU) {
                        v = 0.5f * v * (1.0f + erff(v * 0.70710678118654752f));
                        v = fminf(fmaxf(v, -10.0f), 10.0f);
                    }
                    store_val(C, (size_t)row * N + (bn + wn + j * 16 + lr), v);
                }
            }
        }
    }
}

extern "C" void kernel_launch(void* const* d_in, const int* in_sizes, int n_in,
                              void* d_out, int out_size, void* d_ws, size_t ws_size,
                              hipStream_t stream) {
    const float* x  = (const float*)d_in[0];
    const float* w1 = (const float*)d_in[1];
    const float* b1 = (const float*)d_in[2];
    const float* w2 = (const float*)d_in[3];
    const float* b2 = (const float*)d_in[4];

    const int M = 64 * 197;   // 12608
    const int Cd = 768;
    const int Hd = 3072;

    // workspace layout (~106 MB total)
    char* ws = (char*)d_ws;
    __hip_bfloat16* xb   = (__hip_bfloat16*)ws;                 // [M, Cd]
    __hip_bfloat16* sgn1 = xb + (size_t)M * Cd;                 // [Hd, Cd]
    __hip_bfloat16* sgn2 = sgn1 + (size_t)Hd * Cd;              // [Cd, Hd]
    float* alpha1 = (float*)(sgn2 + (size_t)Cd * Hd);           // [Hd]
    float* alpha2 = alpha1 + Hd;                                // [Cd]
    __hip_bfloat16* hbuf = (__hip_bfloat16*)(alpha2 + Cd);      // [M, Hd]

    // prep: 1280 x-convert blocks (grid-stride) + 960 wave-per-row blocks
    const int nx8 = (M * Cd) / 8;          // 1,210,368 (exact)
    const int NBX = 1280;
    const int NBW = (3072 + 768) / 4;      // 960
    prep_all<<<NBX + NBW, 256, 0, stream>>>(
        x, w1, w2, xb, sgn1, alpha1, sgn2, alpha2, nx8, NBX);

    const int gm = (M + 127) / 128;        // 99

    // GEMM1: 24x99 = 2376 tiles; perXcd = 297 (exact)
    {
        const int T = (Hd / 128) * gm;
        const int perXcd = (T + 7) / 8;
        gemm_bin<true, __hip_bfloat16><<<perXcd * 8, 256, 0, stream>>>(
            xb, sgn1, alpha1, b1, hbuf, M, Hd, Cd, T, perXcd);
    }
    // GEMM2: 6x99 = 594 tiles; perXcd = 75, grid 600 (6 idle blocks)
    {
        const int T = (Cd / 128) * gm;
        const int perXcd = (T + 7) / 8;
        gemm_bin<false, float><<<perXcd * 8, 256, 0, stream>>>(
            hbuf, sgn2, alpha2, b2, (float*)d_out, M, Cd, Hd, T, perXcd);
    }
}